// Round 1
// baseline (45.615 us; speedup 1.0000x reference)
//
#include <hip/hip_runtime.h>
#include <hip/hip_bf16.h>

// Problem constants (from reference setup_inputs):
//   x: [B=4, NC=2000, F=4, H=64] fp32
//   fine_to_coarse: [NF=50000] int32 in [0, NC)
//   out: [B=4, NF=50000, F=4, H=64] fp32
// Row size per (b, node) = F*H = 256 floats = 1024 B = 64 float4.

#define B_  4
#define NC_ 2000
#define NF_ 50000
#define ROW_F4 64   // float4 elements per row (F*H/4)

__global__ __launch_bounds__(256) void unpool_gather_kernel(
    const float4* __restrict__ x,      // [B, NC, 64] float4
    const int*    __restrict__ ftc,    // [NF]
    float4*       __restrict__ out)    // [B, NF, 64] float4
{
    const int b   = blockIdx.y;
    const int idx = blockIdx.x * blockDim.x + threadIdx.x;  // over NF_*64
    const int nf    = idx >> 6;        // wave-uniform (64 lanes per row)
    const int inner = idx & 63;

    const int c = ftc[nf];             // broadcast load within the wave

    const float4 v = x[((size_t)b * NC_ + c) * ROW_F4 + inner];
    out[((size_t)b * NF_ + nf) * ROW_F4 + inner] = v;
}

extern "C" void kernel_launch(void* const* d_in, const int* in_sizes, int n_in,
                              void* d_out, int out_size, void* d_ws, size_t ws_size,
                              hipStream_t stream) {
    const float4* x   = (const float4*)d_in[0];
    const int*    ftc = (const int*)d_in[1];
    float4*       out = (float4*)d_out;

    // NF_*64 float4 elements per batch; 256 threads/block -> 12500 blocks per b.
    dim3 grid((NF_ * 64) / 256, B_);
    dim3 block(256);
    unpool_gather_kernel<<<grid, block, 0, stream>>>(x, ftc, out);
}